// Round 27
// baseline (108.069 us; speedup 1.0000x reference)
//
#include <hip/hip_runtime.h>
#include <math.h>

#define D_MODEL 1024
#define D_HEAD  64
#define N_HEADS 16
#define COND_F  768
#define BATCH   2
#define SEQ     2048
#define NTOK    (BATCH*SEQ)      /* 4096 */
#define QKV_N   (3*D_MODEL)      /* 3072 */

typedef unsigned short u16;
typedef __attribute__((ext_vector_type(4))) float  f32x4;
typedef __attribute__((ext_vector_type(8))) __bf16 bfrag;   // MFMA A/B operand (4 VGPRs)
typedef __attribute__((ext_vector_type(4))) unsigned short u16x4;
typedef __attribute__((ext_vector_type(8))) unsigned short u16x8;

__device__ __forceinline__ u16 f2bf(float f) {
    unsigned u = __builtin_bit_cast(unsigned, f);
    return (u16)((u + 0x7fffu + ((u >> 16) & 1u)) >> 16);
}
__device__ __forceinline__ float bf2f(u16 h) {
    unsigned u = ((unsigned)h) << 16;
    return __builtin_bit_cast(float, u);
}

// raw v_exp_f32 (= 2^x). Inputs are pre-bounded (|x| <= ~14.5).
__device__ __forceinline__ float fexp2(float x) {
    float y;
    asm("v_exp_f32 %0, %1" : "=v"(y) : "v"(x));
    return y;
}

__device__ __forceinline__ void async16(const void* g, void* l) {
    __builtin_amdgcn_global_load_lds(
        (const __attribute__((address_space(1))) unsigned int*)g,
        (__attribute__((address_space(3))) unsigned int*)l, 16, 0, 0);
}

// counted-vmcnt pipeline primitives: raw barrier (no implicit vmcnt drain),
// sched_barrier fences so the compiler can't move LDS ops across it.
#define SBAR do { __builtin_amdgcn_sched_barrier(0); \
                  __builtin_amdgcn_s_barrier(); \
                  __builtin_amdgcn_sched_barrier(0); } while (0)
#define WAITV3 do { asm volatile("s_waitcnt vmcnt(3)" ::: "memory"); } while (0)
#define WAITV2 do { asm volatile("s_waitcnt vmcnt(2)" ::: "memory"); } while (0)
#define WAITV0 do { asm volatile("s_waitcnt vmcnt(0)" ::: "memory"); } while (0)

// ---------------------------------------------------------------- prep: weights->bf16 + cond scale + rope table
// RoPE table deduped across batch (pos[b,s] = s for all b): (s,h,j) only.
__global__ __launch_bounds__(256) void prep_kernel(const float* __restrict__ wqkv,
                                                   const float* __restrict__ wout,
                                                   u16* __restrict__ wqkv_b,
                                                   u16* __restrict__ wout_b,
                                                   const float* __restrict__ cond,
                                                   const float* __restrict__ w_norm,
                                                   float* __restrict__ cs,
                                                   const float* __restrict__ pos,
                                                   float2* __restrict__ tab) {
    if (blockIdx.x < 2048) {
        int i = blockIdx.x * 256 + threadIdx.x;       // one per 8 elements
        const int n1 = QKV_N * D_MODEL / 8;           // 393216
        const float* src; u16* dst; int off;
        if (i < n1) { src = wqkv; dst = wqkv_b; off = i * 8; }
        else        { src = wout; dst = wout_b; off = (i - n1) * 8; }
        float4 a = *(const float4*)(src + off);
        float4 b = *(const float4*)(src + off + 4);
        *(u16x4*)(dst + off)     = (u16x4){f2bf(a.x), f2bf(a.y), f2bf(a.z), f2bf(a.w)};
        *(u16x4*)(dst + off + 4) = (u16x4){f2bf(b.x), f2bf(b.y), f2bf(b.z), f2bf(b.w)};
    } else if (blockIdx.x < 2560) {
        // cond GEMV: one wave per output element (b,d)
        int lane = threadIdx.x & 63, w = threadIdx.x >> 6;
        int wid = (blockIdx.x - 2048) * 4 + w;        // 0..2047
        int b = wid >> 10, d = wid & 1023;
        const float* c = cond + b * COND_F;
        const float* wn = w_norm + (size_t)d * COND_F;
        float acc = 0.f;
        #pragma unroll
        for (int kk = 0; kk < 3; ++kk) {
            int j = kk * 256 + lane * 4;
            float4 cv = *(const float4*)(c + j);
            float4 wv = *(const float4*)(wn + j);
            acc += cv.x * wv.x + cv.y * wv.y + cv.z * wv.z + cv.w * wv.w;
        }
        for (int m = 1; m < 64; m <<= 1) acc += __shfl_xor(acc, m);
        if (lane == 0) cs[wid] = acc + 1.0f;
    } else {
        // RoPE cos/sin table: i -> (s, h, j); pos is batch-broadcast arange so
        // the (b) dimension is redundant. Same fp32 math as the old postqk.
        int i = (blockIdx.x - 2560) * 256 + threadIdx.x;   // 0..262143
        int j = i & 7, h = (i >> 3) & 15;
        int s = i >> 7;                                    // 0..2047
        // freqs[h][j] = exp(log(pi) + (j*16+h)*ln(10)/128), fp64 to match np
        double lf = 1.1447298858494001741 + (double)(j * 16 + h) * (2.302585092994045684 / 128.0);
        float fr = (float)exp(lf);
        float th = pos[s] * fr;
        tab[i] = make_float2(cosf(th), sinf(th));
    }
}

// ---------------------------------------------------------------- RMSNorm * cond_scale -> bf16
__global__ __launch_bounds__(256) void rmsnorm_kernel(const float* __restrict__ x,
                                                      const float* __restrict__ cs,
                                                      u16* __restrict__ xn) {
    int tok = blockIdx.x, t = threadIdx.x;
    int b = tok >> 11;
    const float* xr = x + (size_t)tok * D_MODEL;
    float4 v = *(const float4*)(xr + t * 4);
    float ss = v.x * v.x + v.y * v.y + v.z * v.z + v.w * v.w;
    for (int m = 1; m < 64; m <<= 1) ss += __shfl_xor(ss, m);
    __shared__ float red[4];
    int w = t >> 6;
    if ((t & 63) == 0) red[w] = ss;
    __syncthreads();
    float tot = red[0] + red[1] + red[2] + red[3];
    float r = rsqrtf(tot * (1.0f / D_MODEL) + 1e-6f);
    float4 cv = *(const float4*)(cs + b * D_MODEL + t * 4);
    *(u16x4*)(xn + (size_t)tok * D_MODEL + t * 4) =
        (u16x4){f2bf(v.x * cv.x * r), f2bf(v.y * cv.y * r),
                f2bf(v.z * cv.z * r), f2bf(v.w * cv.w * r)};
}

// ---------------------------------------------------------------- QKV GEMM: 128x128, 8 waves, 32x64/wave
// R20 form: single-barrier 3-buffer ring, no setprio (R21 A/B: setprio hurt).
// Fused epilogue: q/k: L2-norm+RoPE -> (b,h,s,e); v -> vt sigma-permuted.
__global__ __launch_bounds__(512) void gemm_qkv(const u16* __restrict__ A, const u16* __restrict__ B,
                                                u16* __restrict__ Cq, u16* __restrict__ Ck,
                                                u16* __restrict__ Cv,
                                                const float* __restrict__ scale,
                                                const float2* __restrict__ tab,
                                                int M, int N, int K) {
    __shared__ u16 As0[128 * 32];
    __shared__ u16 As1[128 * 32];
    __shared__ u16 As2[128 * 32];
    __shared__ u16 Bs0[128 * 32];
    __shared__ u16 Bs1[128 * 32];
    __shared__ u16 Bs2[128 * 32];
    int tid = threadIdx.x;
    int lane = tid & 63, w = tid >> 6;
    int wr = w >> 1, wc = w & 1;                      // 4 (M) x 2 (N) waves
    int m0 = blockIdx.x * 128, n0 = blockIdx.y * 128;
    f32x4 acc[2][4] = {};
    const u16* Ag = A + (size_t)m0 * K;
    const u16* Bg = B + (size_t)n0 * K;
    int lr = lane & 15, lq = lane >> 4;

    int srow = tid >> 2, scol = (tid & 3) * 8;        // 512 threads cover 128x32

    #define GSTAGE(kt, Ad, Bd) do { \
        async16(Ag + (size_t)srow * K + (kt) + scol, Ad + tid * 8); \
        async16(Bg + (size_t)srow * K + (kt) + scol, Bd + tid * 8); } while (0)

    auto compute = [&](const u16* Asb, const u16* Bsb) {
        bfrag af[2], bfv[4];
        #pragma unroll
        for (int fm = 0; fm < 2; ++fm)
            af[fm] = *(const bfrag*)&Asb[(wr * 32 + fm * 16 + lr) * 32 + lq * 8];
        #pragma unroll
        for (int fn = 0; fn < 4; ++fn)
            bfv[fn] = *(const bfrag*)&Bsb[(wc * 64 + fn * 16 + lr) * 32 + lq * 8];
        #pragma unroll
        for (int fm = 0; fm < 2; ++fm)
            #pragma unroll
            for (int fn = 0; fn < 4; ++fn)
                acc[fm][fn] = __builtin_amdgcn_mfma_f32_16x16x32_bf16(af[fm], bfv[fn], acc[fm][fn], 0, 0, 0);
    };

    const int NK = K / 32;                            // 32 (NK % 3 == 2)
    GSTAGE(0, As0, Bs0);
    GSTAGE(32, As1, Bs1);

    for (int t = 0; t < NK - 2; t += 3) {
        WAITV2; SBAR; GSTAGE((size_t)(t + 2) * 32, As2, Bs2); compute(As0, Bs0);
        WAITV2; SBAR; GSTAGE((size_t)(t + 3) * 32, As0, Bs0); compute(As1, Bs1);
        WAITV2; SBAR; GSTAGE((size_t)(t + 4) * 32, As1, Bs1); compute(As2, Bs2);
    }
    // tail: tiles NK-2 (buf0), NK-1 (buf1); no further staging
    WAITV2; SBAR; compute(As0, Bs0);
    WAITV0; SBAR; compute(As1, Bs1);
    #undef GSTAGE

    int colbase0 = n0 + wc * 64;            // wave-invariant; one head per (block,wc)
    int sel = colbase0 >> 10;
    int h = (colbase0 >> 6) & 15;
    int bb = m0 >> 11;
    if (sel == 2) {
        #pragma unroll
        for (int fm = 0; fm < 2; ++fm) {
            int sP = (m0 & 2047) + wr * 32 + 8 * lq + 4 * fm;
            #pragma unroll
            for (int fn = 0; fn < 4; ++fn) {
                int e = fn * 16 + lr;
                u16x4 pk = {f2bf(acc[fm][fn][0]), f2bf(acc[fm][fn][1]),
                            f2bf(acc[fm][fn][2]), f2bf(acc[fm][fn][3])};
                *(u16x4*)&Cv[((size_t)(bb * N_HEADS + h) * D_HEAD + e) * SEQ + sP] = pk;
            }
        }
    } else {
        // fused L2-norm + RoPE (identical math to the old postqk kernel)
        u16* p = sel ? Ck : Cq;
        float sq = sqrtf(scale[h]);
        float mult = (sel == 0) ? sq * 1.4426950408889634f : sq;  // fold log2e into q
        #pragma unroll
        for (int fm = 0; fm < 2; ++fm) {
            int s0 = (m0 & 2047) + wr * 32 + fm * 16 + lq * 4;
            #pragma unroll
            for (int r = 0; r < 4; ++r) {
                float v0 = acc[fm][0][r], v1 = acc[fm][1][r],
                      v2 = acc[fm][2][r], v3 = acc[fm][3][r];
                float ss = v0 * v0 + v1 * v1 + v2 * v2 + v3 * v3;
                ss += __shfl_xor(ss, 1); ss += __shfl_xor(ss, 2);
                ss += __shfl_xor(ss, 4); ss += __shfl_xor(ss, 8);   // sum over 16 lr lanes
                float rs = mult * rsqrtf(ss + 1e-6f);
                v0 *= rs; v1 *= rs; v2 *= rs; v3 *= rs;
                // RoPE on e<16 (fn==0 frag): pair (e, e+8) via xor-8 shuffle
                float part = __shfl_xor(v0, 8);
                float2 cs2 = tab[((size_t)(s0 + r) * 16 + h) * 8 + (lr & 7)];
                v0 = (lr < 8) ? v0 * cs2.x - part * cs2.y
                              : v0 * cs2.x + part * cs2.y;
                size_t rp = ((size_t)(bb * N_HEADS + h) * SEQ + (s0 + r)) * D_HEAD;
                p[rp + lr]      = f2bf(v0);
                p[rp + 16 + lr] = f2bf(v1);
                p[rp + 32 + lr] = f2bf(v2);
                p[rp + 48 + lr] = f2bf(v3);
            }
        }
    }
}

// ---------------------------------------------------------------- out-proj GEMM: 128x64, 4 waves, 32x64/wave
// R21-validated: grid 512 = 2 blocks/CU. Single-barrier 3-buffer ring,
// 3 loads/thread/tile -> WAITV3 steady-state. fp32 out = C + skip.
__global__ __launch_bounds__(256) void gemm_out(const u16* __restrict__ A, const u16* __restrict__ B,
                                                float* __restrict__ Cf,
                                                const float* __restrict__ skip,
                                                int M, int N, int K) {
    __shared__ u16 As0[128 * 32];
    __shared__ u16 As1[128 * 32];
    __shared__ u16 As2[128 * 32];
    __shared__ u16 Bs0[64 * 32];
    __shared__ u16 Bs1[64 * 32];
    __shared__ u16 Bs2[64 * 32];
    int tid = threadIdx.x;
    int lane = tid & 63, w = tid >> 6;                // 4 waves: wr = w, wc = 0
    int m0 = blockIdx.x * 128, n0 = blockIdx.y * 64;
    f32x4 acc[2][4] = {};
    const u16* Ag = A + (size_t)m0 * K;
    const u16* Bg = B + (size_t)n0 * K;
    int lr = lane & 15, lq = lane >> 4;

    int c1 = 256 + tid;

    #define GSTAGE(kt, Ad, Bd) do { \
        async16(Ag + (size_t)(tid >> 2) * K + (kt) + (tid & 3) * 8, Ad + tid * 8); \
        async16(Ag + (size_t)(c1 >> 2) * K + (kt) + (c1 & 3) * 8, Ad + c1 * 8); \
        async16(Bg + (size_t)(tid >> 2) * K + (kt) + (tid & 3) * 8, Bd + tid * 8); } while (0)

    auto compute = [&](const u16* Asb, const u16* Bsb) {
        bfrag af[2], bfv[4];
        #pragma unroll
        for (int fm = 0; fm < 2; ++fm)
            af[fm] = *(const bfrag*)&Asb[(w * 32 + fm * 16 + lr) * 32 + lq * 8];
        #pragma unroll
        for (int fn = 0; fn < 4; ++fn)
            bfv[fn] = *(const bfrag*)&Bsb[(fn * 16 + lr) * 32 + lq * 8];
        #pragma unroll
        for (int fm = 0; fm < 2; ++fm)
            #pragma unroll
            for (int fn = 0; fn < 4; ++fn)
                acc[fm][fn] = __builtin_amdgcn_mfma_f32_16x16x32_bf16(af[fm], bfv[fn], acc[fm][fn], 0, 0, 0);
    };

    const int NK = K / 32;                            // 32 (NK % 3 == 2)
    GSTAGE(0, As0, Bs0);
    GSTAGE(32, As1, Bs1);

    for (int t = 0; t < NK - 2; t += 3) {
        WAITV3; SBAR; GSTAGE((size_t)(t + 2) * 32, As2, Bs2); compute(As0, Bs0);
        WAITV3; SBAR; GSTAGE((size_t)(t + 3) * 32, As0, Bs0); compute(As1, Bs1);
        WAITV3; SBAR; GSTAGE((size_t)(t + 4) * 32, As1, Bs1); compute(As2, Bs2);
    }
    WAITV3; SBAR; compute(As0, Bs0);
    WAITV0; SBAR; compute(As1, Bs1);
    #undef GSTAGE

    #pragma unroll
    for (int fm = 0; fm < 2; ++fm) {
        int rowbase = m0 + w * 32 + fm * 16 + lq * 4;
        #pragma unroll
        for (int fn = 0; fn < 4; ++fn) {
            int col = n0 + fn * 16 + lr;
            #pragma unroll
            for (int r = 0; r < 4; ++r) {
                int row = rowbase + r;
                Cf[(size_t)row * N + col] = acc[fm][fn][r] + skip[(size_t)row * N + col];
            }
        }
    }
}

// ---------------------------------------------------------------- flash attention, NO split (Z=1), 4-wave
// Swapped QK^T (A=K, B=Q); P built in-register (sigma absorbed into vt).
// QBLK=128 / 4 waves / 256 threads -> 512 blocks = 2 blocks/CU (cross-block
// barrier cover preserved). Full KV per block; row sums are lane-replicated
// so normalization happens in-register and the FINAL bf16 output is written
// directly -- no partials, no combine kernel.
__global__ __launch_bounds__(256) void attn_kernel(const u16* __restrict__ q,
                                                   const u16* __restrict__ k,
                                                   const u16* __restrict__ vt,
                                                   u16* __restrict__ o) {
    __shared__ u16 Ks0[64 * 64];
    __shared__ u16 Ks1[64 * 64];
    __shared__ u16 Vs0[64 * 64];
    __shared__ u16 Vs1[64 * 64];
    int tid = threadIdx.x, lane = tid & 63, w = tid >> 6;   // w in [0,4)

    // XCD swizzle (m157 transform; nwg=512, nwg%8==0): the 16 qs-sharers of
    // one bh's K/V are contiguous wids within a 64-block -> co-XCD; 4 bh per
    // XCD = 2 MB K/V per L2.
    int rid = blockIdx.x;
    int nwg = gridDim.x, cpx = nwg >> 3;          // 64
    int wid = (rid & 7) * cpx + (rid >> 3);
    int xq = wid & 15;                            // 16 q-blocks of 128 rows
    int bh = wid >> 4;                            // 0..31
    int qs = xq * 128;
    int lr = lane & 15, lq = lane >> 4;

    bfrag qf[2][2];
    #pragma unroll
    for (int mf = 0; mf < 2; ++mf) {
        const u16* qb = q + ((size_t)bh * SEQ + qs + w * 32 + mf * 16 + lr) * D_HEAD + lq * 8;
        qf[mf][0] = *(const bfrag*)qb;
        qf[mf][1] = *(const bfrag*)(qb + 32);
    }
    bfrag ones;
    #pragma unroll
    for (int j = 0; j < 8; ++j) ones[j] = (__bf16)1.0f;

    f32x4 oacc[2][4] = {};
    f32x4 oacc5[2] = {};                 // row sums (replicated over lr)
    const u16* kbase = k + (size_t)bh * SEQ * D_HEAD;
    const u16* vbase = vt + (size_t)bh * D_HEAD * SEQ;

    // staging: 256 threads x 2 chunks cover one 64x64 K tile + one V tile
    int c1t = tid + 256;
    int sr0 = tid >> 3, sc0 = (tid & 7) ^ ((tid >> 3) & 7);     // pre-swizzled source
    int sr1 = c1t >> 3, sc1 = (c1t & 7) ^ ((c1t >> 3) & 7);
    const u16* kg0 = kbase + (size_t)sr0 * 64 + sc0 * 8;        // + kt*64 per tile
    const u16* kg1 = kbase + (size_t)sr1 * 64 + sc1 * 8;
    const u16* vg0 = vbase + (size_t)sr0 * SEQ + sc0 * 8;       // + kt per tile
    const u16* vg1 = vbase + (size_t)sr1 * SEQ + sc1 * 8;

    #define STAGE(kt, Kd, Vd) do { \
        async16(kg0 + (size_t)(kt) * 64, Kd + tid * 8); \
        async16(kg1 + (size_t)(kt) * 64, Kd + c1t * 8); \
        async16(vg0 + (kt),              Vd + tid * 8); \
        async16(vg1 + (kt),              Vd + c1t * 8); } while (0)

    auto tile_compute = [&](const u16* Kb, const u16* Vb) {
        // swapped QK^T: sacc[mf][nb] = D[kv-local][q] ; kf is the A operand
        f32x4 sacc[2][4] = {};
        __builtin_amdgcn_s_setprio(1);
        #pragma unroll
        for (int nb = 0; nb < 4; ++nb) {
            int row = nb * 16 + lr;
            #pragma unroll
            for (int kb = 0; kb < 2; ++kb) {
                bfrag kf = *(const bfrag*)&Kb[row * 64 + (((kb * 4 + lq) ^ (row & 7)) * 8)];
                sacc[0][nb] = __builtin_amdgcn_mfma_f32_16x16x32_bf16(kf, qf[0][kb], sacc[0][nb], 0, 0, 0);
                sacc[1][nb] = __builtin_amdgcn_mfma_f32_16x16x32_bf16(kf, qf[1][kb], sacc[1][nb], 0, 0, 0);
            }
        }
        __builtin_amdgcn_s_setprio(0);

        // per-kb: exp + pack, then immediately its PV MFMAs (kb=1 exp overlaps kb=0 PV)
        #pragma unroll
        for (int kb = 0; kb < 2; ++kb) {
            bfrag pf[2];
            #pragma unroll
            for (int mf = 0; mf < 2; ++mf)
                #pragma unroll
                for (int half = 0; half < 2; ++half) {
                    int nb = kb * 2 + half;
                    #pragma unroll
                    for (int r = 0; r < 4; ++r)
                        pf[mf][half * 4 + r] = (__bf16)fexp2(sacc[mf][nb][r]);
                }
            __builtin_amdgcn_s_setprio(1);
            oacc5[0] = __builtin_amdgcn_mfma_f32_16x16x32_bf16(pf[0], ones, oacc5[0], 0, 0, 0);
            oacc5[1] = __builtin_amdgcn_mfma_f32_16x16x32_bf16(pf[1], ones, oacc5[1], 0, 0, 0);
            #pragma unroll
            for (int eb = 0; eb < 4; ++eb) {
                int row = eb * 16 + lr;
                bfrag vf = *(const bfrag*)&Vb[row * 64 + (((kb * 4 + lq) ^ (row & 7)) * 8)];
                oacc[0][eb] = __builtin_amdgcn_mfma_f32_16x16x32_bf16(pf[0], vf, oacc[0][eb], 0, 0, 0);
                oacc[1][eb] = __builtin_amdgcn_mfma_f32_16x16x32_bf16(pf[1], vf, oacc[1][eb], 0, 0, 0);
            }
            __builtin_amdgcn_s_setprio(0);
        }
    };

    STAGE(0, Ks0, Vs0);
    asm volatile("s_waitcnt vmcnt(0)" ::: "memory");
    __syncthreads();

    const int NTILE = SEQ / 64;                        // 32, even
    for (int t = 0; t < NTILE; t += 2) {
        if (t + 1 < NTILE) STAGE((t + 1) * 64, Ks1, Vs1);
        tile_compute(Ks0, Vs0);
        __syncthreads();
        if (t + 2 < NTILE) STAGE((t + 2) * 64, Ks0, Vs0);
        if (t + 1 < NTILE) {
            tile_compute(Ks1, Vs1);
            __syncthreads();
        }
    }
    #undef STAGE

    // in-register normalization (row sums replicated across lr lanes) ->
    // final bf16 output directly, no partials.
    int b = bh >> 4, h = bh & 15;
    #pragma unroll
    for (int mf = 0; mf < 2; ++mf) {
        #pragma unroll
        for (int r = 0; r < 4; ++r) {
            float inv = 1.0f / oacc5[mf][r];
            int qrow = qs + w * 32 + mf * 16 + lq * 4 + r;
            #pragma unroll
            for (int eb = 0; eb < 4; ++eb) {
                int e = eb * 16 + lr;
                o[((size_t)b * SEQ + qrow) * D_MODEL + h * D_HEAD + e] = f2bf(oacc[mf][eb][r] * inv);
            }
        }
    }
}

// ---------------------------------------------------------------- launcher
extern "C" void kernel_launch(void* const* d_in, const int* in_sizes, int n_in,
                              void* d_out, int out_size, void* d_ws, size_t ws_size,
                              hipStream_t stream) {
    const float* x      = (const float*)d_in[0];
    const float* pos    = (const float*)d_in[1];
    const float* cond   = (const float*)d_in[2];
    const float* w_norm = (const float*)d_in[3];
    const float* w_qkv  = (const float*)d_in[4];
    const float* scale  = (const float*)d_in[5];
    const float* w_out  = (const float*)d_in[6];
    float* out = (float*)d_out;

    char* ws = (char*)d_ws;
    u16* xn     = (u16*)ws;                               // 8 MB (aliased by attn_o later)
    u16* wqkv_b = (u16*)(ws + (8u  << 20));               // 6 MB
    u16* wout_b = (u16*)(ws + (14u << 20));               // 2 MB
    float* cs   = (float*)(ws + (16u << 20));             // 8 KB
    u16* qb     = (u16*)(ws + (16u << 20) + (1u << 16));  // 8 MB
    const size_t HSZ = (size_t)BATCH * N_HEADS * SEQ * D_HEAD;
    u16* kb = qb + HSZ;                                   // 8 MB
    u16* vt = kb + HSZ;                                   // 8 MB (written permuted-transposed by gemm)
    float2* tab = (float2*)(ws + (41u << 20));            // 2 MB rope table
    u16* attn_o = xn;                                     // alias: xn dead after QKV GEMM

    prep_kernel<<<dim3(3584), dim3(256), 0, stream>>>(w_qkv, w_out, wqkv_b, wout_b,
                                                      cond, w_norm, cs, pos, (float2*)tab);
    rmsnorm_kernel<<<dim3(NTOK), dim3(256), 0, stream>>>(x, cs, xn);
    gemm_qkv<<<dim3(NTOK / 128, QKV_N / 128), dim3(512), 0, stream>>>(
        xn, wqkv_b, qb, kb, vt, scale, (const float2*)tab, NTOK, QKV_N, D_MODEL);
    attn_kernel<<<dim3(512), dim3(256), 0, stream>>>(qb, kb, vt, attn_o);
    gemm_out<<<dim3(NTOK / 128, D_MODEL / 64), dim3(256), 0, stream>>>(
        attn_o, wout_b, out, x, NTOK, D_MODEL, D_MODEL);
}

// Round 28
// 106.366 us; speedup vs baseline: 1.0160x; 1.0160x over previous
//
#include <hip/hip_runtime.h>
#include <math.h>

#define D_MODEL 1024
#define D_HEAD  64
#define N_HEADS 16
#define COND_F  768
#define BATCH   2
#define SEQ     2048
#define NTOK    (BATCH*SEQ)      /* 4096 */
#define QKV_N   (3*D_MODEL)      /* 3072 */

typedef unsigned short u16;
typedef __attribute__((ext_vector_type(4))) float  f32x4;
typedef __attribute__((ext_vector_type(8))) __bf16 bfrag;   // MFMA A/B operand (4 VGPRs)
typedef __attribute__((ext_vector_type(4))) unsigned short u16x4;
typedef __attribute__((ext_vector_type(8))) unsigned short u16x8;

__device__ __forceinline__ u16 f2bf(float f) {
    unsigned u = __builtin_bit_cast(unsigned, f);
    return (u16)((u + 0x7fffu + ((u >> 16) & 1u)) >> 16);
}
__device__ __forceinline__ float bf2f(u16 h) {
    unsigned u = ((unsigned)h) << 16;
    return __builtin_bit_cast(float, u);
}

// raw v_exp_f32 (= 2^x). Inputs are pre-bounded (|x| <= ~14.5).
__device__ __forceinline__ float fexp2(float x) {
    float y;
    asm("v_exp_f32 %0, %1" : "=v"(y) : "v"(x));
    return y;
}

__device__ __forceinline__ void async16(const void* g, void* l) {
    __builtin_amdgcn_global_load_lds(
        (const __attribute__((address_space(1))) unsigned int*)g,
        (__attribute__((address_space(3))) unsigned int*)l, 16, 0, 0);
}

// counted-vmcnt pipeline primitives: raw barrier (no implicit vmcnt drain),
// sched_barrier fences so the compiler can't move LDS ops across it.
#define SBAR do { __builtin_amdgcn_sched_barrier(0); \
                  __builtin_amdgcn_s_barrier(); \
                  __builtin_amdgcn_sched_barrier(0); } while (0)
#define WAITV3 do { asm volatile("s_waitcnt vmcnt(3)" ::: "memory"); } while (0)
#define WAITV2 do { asm volatile("s_waitcnt vmcnt(2)" ::: "memory"); } while (0)
#define WAITV0 do { asm volatile("s_waitcnt vmcnt(0)" ::: "memory"); } while (0)

// ---------------------------------------------------------------- prep: weights->bf16 + cond scale + rope table
// RoPE table deduped across batch (pos[b,s] = s for all b): (s,h,j) only.
__global__ __launch_bounds__(256) void prep_kernel(const float* __restrict__ wqkv,
                                                   const float* __restrict__ wout,
                                                   u16* __restrict__ wqkv_b,
                                                   u16* __restrict__ wout_b,
                                                   const float* __restrict__ cond,
                                                   const float* __restrict__ w_norm,
                                                   float* __restrict__ cs,
                                                   const float* __restrict__ pos,
                                                   float2* __restrict__ tab) {
    if (blockIdx.x < 2048) {
        int i = blockIdx.x * 256 + threadIdx.x;       // one per 8 elements
        const int n1 = QKV_N * D_MODEL / 8;           // 393216
        const float* src; u16* dst; int off;
        if (i < n1) { src = wqkv; dst = wqkv_b; off = i * 8; }
        else        { src = wout; dst = wout_b; off = (i - n1) * 8; }
        float4 a = *(const float4*)(src + off);
        float4 b = *(const float4*)(src + off + 4);
        *(u16x4*)(dst + off)     = (u16x4){f2bf(a.x), f2bf(a.y), f2bf(a.z), f2bf(a.w)};
        *(u16x4*)(dst + off + 4) = (u16x4){f2bf(b.x), f2bf(b.y), f2bf(b.z), f2bf(b.w)};
    } else if (blockIdx.x < 2560) {
        // cond GEMV: one wave per output element (b,d)
        int lane = threadIdx.x & 63, w = threadIdx.x >> 6;
        int wid = (blockIdx.x - 2048) * 4 + w;        // 0..2047
        int b = wid >> 10, d = wid & 1023;
        const float* c = cond + b * COND_F;
        const float* wn = w_norm + (size_t)d * COND_F;
        float acc = 0.f;
        #pragma unroll
        for (int kk = 0; kk < 3; ++kk) {
            int j = kk * 256 + lane * 4;
            float4 cv = *(const float4*)(c + j);
            float4 wv = *(const float4*)(wn + j);
            acc += cv.x * wv.x + cv.y * wv.y + cv.z * wv.z + cv.w * wv.w;
        }
        for (int m = 1; m < 64; m <<= 1) acc += __shfl_xor(acc, m);
        if (lane == 0) cs[wid] = acc + 1.0f;
    } else {
        // RoPE cos/sin table: i -> (s, h, j); pos is batch-broadcast arange so
        // the (b) dimension is redundant. Same fp32 math as the old postqk.
        int i = (blockIdx.x - 2560) * 256 + threadIdx.x;   // 0..262143
        int j = i & 7, h = (i >> 3) & 15;
        int s = i >> 7;                                    // 0..2047
        // freqs[h][j] = exp(log(pi) + (j*16+h)*ln(10)/128), fp64 to match np
        double lf = 1.1447298858494001741 + (double)(j * 16 + h) * (2.302585092994045684 / 128.0);
        float fr = (float)exp(lf);
        float th = pos[s] * fr;
        tab[i] = make_float2(cosf(th), sinf(th));
    }
}

// ---------------------------------------------------------------- RMSNorm * cond_scale -> bf16
__global__ __launch_bounds__(256) void rmsnorm_kernel(const float* __restrict__ x,
                                                      const float* __restrict__ cs,
                                                      u16* __restrict__ xn) {
    int tok = blockIdx.x, t = threadIdx.x;
    int b = tok >> 11;
    const float* xr = x + (size_t)tok * D_MODEL;
    float4 v = *(const float4*)(xr + t * 4);
    float ss = v.x * v.x + v.y * v.y + v.z * v.z + v.w * v.w;
    for (int m = 1; m < 64; m <<= 1) ss += __shfl_xor(ss, m);
    __shared__ float red[4];
    int w = t >> 6;
    if ((t & 63) == 0) red[w] = ss;
    __syncthreads();
    float tot = red[0] + red[1] + red[2] + red[3];
    float r = rsqrtf(tot * (1.0f / D_MODEL) + 1e-6f);
    float4 cv = *(const float4*)(cs + b * D_MODEL + t * 4);
    *(u16x4*)(xn + (size_t)tok * D_MODEL + t * 4) =
        (u16x4){f2bf(v.x * cv.x * r), f2bf(v.y * cv.y * r),
                f2bf(v.z * cv.z * r), f2bf(v.w * cv.w * r)};
}

// ---------------------------------------------------------------- QKV GEMM: 128x128, 8 waves, 32x64/wave
// R20 form: single-barrier 3-buffer ring, no setprio (R21 A/B: setprio hurt).
// Fused epilogue: q/k: L2-norm+RoPE -> (b,h,s,e); v -> vt sigma-permuted.
__global__ __launch_bounds__(512) void gemm_qkv(const u16* __restrict__ A, const u16* __restrict__ B,
                                                u16* __restrict__ Cq, u16* __restrict__ Ck,
                                                u16* __restrict__ Cv,
                                                const float* __restrict__ scale,
                                                const float2* __restrict__ tab,
                                                int M, int N, int K) {
    __shared__ u16 As0[128 * 32];
    __shared__ u16 As1[128 * 32];
    __shared__ u16 As2[128 * 32];
    __shared__ u16 Bs0[128 * 32];
    __shared__ u16 Bs1[128 * 32];
    __shared__ u16 Bs2[128 * 32];
    int tid = threadIdx.x;
    int lane = tid & 63, w = tid >> 6;
    int wr = w >> 1, wc = w & 1;                      // 4 (M) x 2 (N) waves
    int m0 = blockIdx.x * 128, n0 = blockIdx.y * 128;
    f32x4 acc[2][4] = {};
    const u16* Ag = A + (size_t)m0 * K;
    const u16* Bg = B + (size_t)n0 * K;
    int lr = lane & 15, lq = lane >> 4;

    int srow = tid >> 2, scol = (tid & 3) * 8;        // 512 threads cover 128x32

    #define GSTAGE(kt, Ad, Bd) do { \
        async16(Ag + (size_t)srow * K + (kt) + scol, Ad + tid * 8); \
        async16(Bg + (size_t)srow * K + (kt) + scol, Bd + tid * 8); } while (0)

    auto compute = [&](const u16* Asb, const u16* Bsb) {
        bfrag af[2], bfv[4];
        #pragma unroll
        for (int fm = 0; fm < 2; ++fm)
            af[fm] = *(const bfrag*)&Asb[(wr * 32 + fm * 16 + lr) * 32 + lq * 8];
        #pragma unroll
        for (int fn = 0; fn < 4; ++fn)
            bfv[fn] = *(const bfrag*)&Bsb[(wc * 64 + fn * 16 + lr) * 32 + lq * 8];
        #pragma unroll
        for (int fm = 0; fm < 2; ++fm)
            #pragma unroll
            for (int fn = 0; fn < 4; ++fn)
                acc[fm][fn] = __builtin_amdgcn_mfma_f32_16x16x32_bf16(af[fm], bfv[fn], acc[fm][fn], 0, 0, 0);
    };

    const int NK = K / 32;                            // 32 (NK % 3 == 2)
    GSTAGE(0, As0, Bs0);
    GSTAGE(32, As1, Bs1);

    for (int t = 0; t < NK - 2; t += 3) {
        WAITV2; SBAR; GSTAGE((size_t)(t + 2) * 32, As2, Bs2); compute(As0, Bs0);
        WAITV2; SBAR; GSTAGE((size_t)(t + 3) * 32, As0, Bs0); compute(As1, Bs1);
        WAITV2; SBAR; GSTAGE((size_t)(t + 4) * 32, As1, Bs1); compute(As2, Bs2);
    }
    // tail: tiles NK-2 (buf0), NK-1 (buf1); no further staging
    WAITV2; SBAR; compute(As0, Bs0);
    WAITV0; SBAR; compute(As1, Bs1);
    #undef GSTAGE

    int colbase0 = n0 + wc * 64;            // wave-invariant; one head per (block,wc)
    int sel = colbase0 >> 10;
    int h = (colbase0 >> 6) & 15;
    int bb = m0 >> 11;
    if (sel == 2) {
        #pragma unroll
        for (int fm = 0; fm < 2; ++fm) {
            int sP = (m0 & 2047) + wr * 32 + 8 * lq + 4 * fm;
            #pragma unroll
            for (int fn = 0; fn < 4; ++fn) {
                int e = fn * 16 + lr;
                u16x4 pk = {f2bf(acc[fm][fn][0]), f2bf(acc[fm][fn][1]),
                            f2bf(acc[fm][fn][2]), f2bf(acc[fm][fn][3])};
                *(u16x4*)&Cv[((size_t)(bb * N_HEADS + h) * D_HEAD + e) * SEQ + sP] = pk;
            }
        }
    } else {
        // fused L2-norm + RoPE (identical math to the old postqk kernel)
        u16* p = sel ? Ck : Cq;
        float sq = sqrtf(scale[h]);
        float mult = (sel == 0) ? sq * 1.4426950408889634f : sq;  // fold log2e into q
        #pragma unroll
        for (int fm = 0; fm < 2; ++fm) {
            int s0 = (m0 & 2047) + wr * 32 + fm * 16 + lq * 4;
            #pragma unroll
            for (int r = 0; r < 4; ++r) {
                float v0 = acc[fm][0][r], v1 = acc[fm][1][r],
                      v2 = acc[fm][2][r], v3 = acc[fm][3][r];
                float ss = v0 * v0 + v1 * v1 + v2 * v2 + v3 * v3;
                ss += __shfl_xor(ss, 1); ss += __shfl_xor(ss, 2);
                ss += __shfl_xor(ss, 4); ss += __shfl_xor(ss, 8);   // sum over 16 lr lanes
                float rs = mult * rsqrtf(ss + 1e-6f);
                v0 *= rs; v1 *= rs; v2 *= rs; v3 *= rs;
                // RoPE on e<16 (fn==0 frag): pair (e, e+8) via xor-8 shuffle
                float part = __shfl_xor(v0, 8);
                float2 cs2 = tab[((size_t)(s0 + r) * 16 + h) * 8 + (lr & 7)];
                v0 = (lr < 8) ? v0 * cs2.x - part * cs2.y
                              : v0 * cs2.x + part * cs2.y;
                size_t rp = ((size_t)(bb * N_HEADS + h) * SEQ + (s0 + r)) * D_HEAD;
                p[rp + lr]      = f2bf(v0);
                p[rp + 16 + lr] = f2bf(v1);
                p[rp + 32 + lr] = f2bf(v2);
                p[rp + 48 + lr] = f2bf(v3);
            }
        }
    }
}

// ---------------------------------------------------------------- out-proj GEMM: 128x64, 4 waves, 32x64/wave
// R21-validated: grid 512 = 2 blocks/CU. Single-barrier 3-buffer ring,
// 3 loads/thread/tile -> WAITV3 steady-state. fp32 out = C + skip.
__global__ __launch_bounds__(256) void gemm_out(const u16* __restrict__ A, const u16* __restrict__ B,
                                                float* __restrict__ Cf,
                                                const float* __restrict__ skip,
                                                int M, int N, int K) {
    __shared__ u16 As0[128 * 32];
    __shared__ u16 As1[128 * 32];
    __shared__ u16 As2[128 * 32];
    __shared__ u16 Bs0[64 * 32];
    __shared__ u16 Bs1[64 * 32];
    __shared__ u16 Bs2[64 * 32];
    int tid = threadIdx.x;
    int lane = tid & 63, w = tid >> 6;                // 4 waves: wr = w, wc = 0
    int m0 = blockIdx.x * 128, n0 = blockIdx.y * 64;
    f32x4 acc[2][4] = {};
    const u16* Ag = A + (size_t)m0 * K;
    const u16* Bg = B + (size_t)n0 * K;
    int lr = lane & 15, lq = lane >> 4;

    int c1 = 256 + tid;

    #define GSTAGE(kt, Ad, Bd) do { \
        async16(Ag + (size_t)(tid >> 2) * K + (kt) + (tid & 3) * 8, Ad + tid * 8); \
        async16(Ag + (size_t)(c1 >> 2) * K + (kt) + (c1 & 3) * 8, Ad + c1 * 8); \
        async16(Bg + (size_t)(tid >> 2) * K + (kt) + (tid & 3) * 8, Bd + tid * 8); } while (0)

    auto compute = [&](const u16* Asb, const u16* Bsb) {
        bfrag af[2], bfv[4];
        #pragma unroll
        for (int fm = 0; fm < 2; ++fm)
            af[fm] = *(const bfrag*)&Asb[(w * 32 + fm * 16 + lr) * 32 + lq * 8];
        #pragma unroll
        for (int fn = 0; fn < 4; ++fn)
            bfv[fn] = *(const bfrag*)&Bsb[(fn * 16 + lr) * 32 + lq * 8];
        #pragma unroll
        for (int fm = 0; fm < 2; ++fm)
            #pragma unroll
            for (int fn = 0; fn < 4; ++fn)
                acc[fm][fn] = __builtin_amdgcn_mfma_f32_16x16x32_bf16(af[fm], bfv[fn], acc[fm][fn], 0, 0, 0);
    };

    const int NK = K / 32;                            // 32 (NK % 3 == 2)
    GSTAGE(0, As0, Bs0);
    GSTAGE(32, As1, Bs1);

    for (int t = 0; t < NK - 2; t += 3) {
        WAITV3; SBAR; GSTAGE((size_t)(t + 2) * 32, As2, Bs2); compute(As0, Bs0);
        WAITV3; SBAR; GSTAGE((size_t)(t + 3) * 32, As0, Bs0); compute(As1, Bs1);
        WAITV3; SBAR; GSTAGE((size_t)(t + 4) * 32, As1, Bs1); compute(As2, Bs2);
    }
    WAITV3; SBAR; compute(As0, Bs0);
    WAITV0; SBAR; compute(As1, Bs1);
    #undef GSTAGE

    #pragma unroll
    for (int fm = 0; fm < 2; ++fm) {
        int rowbase = m0 + w * 32 + fm * 16 + lq * 4;
        #pragma unroll
        for (int fn = 0; fn < 4; ++fn) {
            int col = n0 + fn * 16 + lr;
            #pragma unroll
            for (int r = 0; r < 4; ++r) {
                int row = rowbase + r;
                Cf[(size_t)row * N + col] = acc[fm][fn][r] + skip[(size_t)row * N + col];
            }
        }
    }
}

// ---------------------------------------------------------------- flash attention, split-KV, 8-wave
// Swapped QK^T (A=K, B=Q); P built in-register (sigma absorbed into vt).
// R13/R22 form: depth-1 prefetch (2-buffer, syncthreads) + XCD-aware remap.
// Z=2: halves o_part write traffic + q re-reads; 512 blocks = 2/CU.
// (R27 falsified Z=1/4-wave: occupancy 16% cost more than combine saved.)
__global__ __launch_bounds__(512) void attn_kernel(const u16* __restrict__ q,
                                                   const u16* __restrict__ k,
                                                   const u16* __restrict__ vt,
                                                   u16* __restrict__ o_part,
                                                   float* __restrict__ lsum_part) {
    __shared__ u16 Ks0[64 * 64];
    __shared__ u16 Ks1[64 * 64];
    __shared__ u16 Vs0[64 * 64];
    __shared__ u16 Vs1[64 * 64];
    int tid = threadIdx.x, lane = tid & 63, w = tid >> 6;

    // XCD swizzle (m157 transform; nwg % 8 == 0): all 8 qs-sharers of one
    // (bh,z) K/V chunk land on the same XCD -> staging hits that XCD's L2.
    int rid = blockIdx.x;
    int nwg = gridDim.x, cpx = nwg >> 3;
    int wid = (rid & 7) * cpx + (rid >> 3);
    int xq = wid & 7;
    int rest = wid >> 3;
    int bh = rest & 31;
    int z = rest >> 5;
    int nz = nwg >> 8;                      // nwg = 256 * Z
    int qs = xq * 256;
    int chunk = SEQ / nz;
    int kv0 = z * chunk;
    int lr = lane & 15, lq = lane >> 4;

    bfrag qf[2][2];
    #pragma unroll
    for (int mf = 0; mf < 2; ++mf) {
        const u16* qb = q + ((size_t)bh * SEQ + qs + w * 32 + mf * 16 + lr) * D_HEAD + lq * 8;
        qf[mf][0] = *(const bfrag*)qb;
        qf[mf][1] = *(const bfrag*)(qb + 32);
    }
    bfrag ones;
    #pragma unroll
    for (int j = 0; j < 8; ++j) ones[j] = (__bf16)1.0f;

    f32x4 oacc[2][4] = {};
    f32x4 oacc5[2] = {};                 // row sums (replicated over lr)
    const u16* kbase = k + (size_t)bh * SEQ * D_HEAD;
    const u16* vbase = vt + (size_t)bh * D_HEAD * SEQ;

    // staging: 512 threads cover one 64x64 K chunk + one V chunk (16B each)
    int srow = tid >> 3, scol = (tid & 7) ^ ((tid >> 3) & 7);   // pre-swizzled source
    const u16* kg = kbase + (size_t)srow * 64 + scol * 8;       // + kt*64 per tile
    const u16* vg = vbase + (size_t)srow * SEQ + scol * 8;      // + kt per tile

    #define STAGE(kt, Kd, Vd) do { \
        async16(kg + (size_t)(kt) * 64, Kd + tid * 8); \
        async16(vg + (kt),              Vd + tid * 8); } while (0)

    auto tile_compute = [&](const u16* Kb, const u16* Vb) {
        // swapped QK^T: sacc[mf][nb] = D[kv-local][q] ; kf is the A operand
        f32x4 sacc[2][4] = {};
        __builtin_amdgcn_s_setprio(1);
        #pragma unroll
        for (int nb = 0; nb < 4; ++nb) {
            int row = nb * 16 + lr;
            #pragma unroll
            for (int kb = 0; kb < 2; ++kb) {
                bfrag kf = *(const bfrag*)&Kb[row * 64 + (((kb * 4 + lq) ^ (row & 7)) * 8)];
                sacc[0][nb] = __builtin_amdgcn_mfma_f32_16x16x32_bf16(kf, qf[0][kb], sacc[0][nb], 0, 0, 0);
                sacc[1][nb] = __builtin_amdgcn_mfma_f32_16x16x32_bf16(kf, qf[1][kb], sacc[1][nb], 0, 0, 0);
            }
        }
        __builtin_amdgcn_s_setprio(0);

        // per-kb: exp + pack, then immediately its PV MFMAs (kb=1 exp overlaps kb=0 PV)
        #pragma unroll
        for (int kb = 0; kb < 2; ++kb) {
            bfrag pf[2];
            #pragma unroll
            for (int mf = 0; mf < 2; ++mf)
                #pragma unroll
                for (int half = 0; half < 2; ++half) {
                    int nb = kb * 2 + half;
                    #pragma unroll
                    for (int r = 0; r < 4; ++r)
                        pf[mf][half * 4 + r] = (__bf16)fexp2(sacc[mf][nb][r]);
                }
            __builtin_amdgcn_s_setprio(1);
            oacc5[0] = __builtin_amdgcn_mfma_f32_16x16x32_bf16(pf[0], ones, oacc5[0], 0, 0, 0);
            oacc5[1] = __builtin_amdgcn_mfma_f32_16x16x32_bf16(pf[1], ones, oacc5[1], 0, 0, 0);
            #pragma unroll
            for (int eb = 0; eb < 4; ++eb) {
                int row = eb * 16 + lr;
                bfrag vf = *(const bfrag*)&Vb[row * 64 + (((kb * 4 + lq) ^ (row & 7)) * 8)];
                oacc[0][eb] = __builtin_amdgcn_mfma_f32_16x16x32_bf16(pf[0], vf, oacc[0][eb], 0, 0, 0);
                oacc[1][eb] = __builtin_amdgcn_mfma_f32_16x16x32_bf16(pf[1], vf, oacc[1][eb], 0, 0, 0);
            }
            __builtin_amdgcn_s_setprio(0);
        }
    };

    STAGE(kv0, Ks0, Vs0);
    asm volatile("s_waitcnt vmcnt(0)" ::: "memory");
    __syncthreads();

    const int NTILE = chunk / 64;                      // 16 (Z=2), even
    for (int t = 0; t < NTILE; t += 2) {
        if (t + 1 < NTILE) STAGE(kv0 + (t + 1) * 64, Ks1, Vs1);
        tile_compute(Ks0, Vs0);
        __syncthreads();
        if (t + 2 < NTILE) STAGE(kv0 + (t + 2) * 64, Ks0, Vs0);
        if (t + 1 < NTILE) {
            tile_compute(Ks1, Vs1);
            __syncthreads();
        }
    }
    #undef STAGE

    int b = bh >> 4, h = bh & 15;
    u16* op = o_part + (size_t)z * NTOK * D_MODEL;
    #pragma unroll
    for (int mf = 0; mf < 2; ++mf) {
        #pragma unroll
        for (int r = 0; r < 4; ++r) {
            int qrow = qs + w * 32 + mf * 16 + lq * 4 + r;
            if (lr == 0)
                lsum_part[((size_t)z * BATCH * N_HEADS + bh) * SEQ + qrow] = oacc5[mf][r];
            #pragma unroll
            for (int eb = 0; eb < 4; ++eb) {
                int e = eb * 16 + lr;
                op[((size_t)b * SEQ + qrow) * D_MODEL + h * D_HEAD + e] = f2bf(oacc[mf][eb][r]);
            }
        }
    }
}

// ---------------------------------------------------------------- combine split-KV partials
__global__ __launch_bounds__(256) void combine_kernel(const u16* __restrict__ o_part,
                                                      const float* __restrict__ lsum_part,
                                                      u16* __restrict__ out, int Z) {
    int i = blockIdx.x * 256 + threadIdx.x;      // one per 8 elements
    int base = i * 8;
    int t = base >> 10, col = base & 1023;
    int b = t >> 11, s = t & 2047, h = col >> 6;
    size_t li = (size_t)(b * N_HEADS + h) * SEQ + s;
    float lsum = 0.f;
    for (int z = 0; z < Z; ++z) lsum += lsum_part[(size_t)z * BATCH * N_HEADS * SEQ + li];
    float inv = 1.0f / lsum;
    float acc[8] = {};
    for (int z = 0; z < Z; ++z) {
        u16x8 a = *(const u16x8*)(o_part + (size_t)z * NTOK * D_MODEL + base);
        #pragma unroll
        for (int j = 0; j < 8; ++j) acc[j] += bf2f(a[j]);
    }
    u16x8 r;
    #pragma unroll
    for (int j = 0; j < 8; ++j) r[j] = f2bf(acc[j] * inv);
    *(u16x8*)(out + base) = r;
}

// ---------------------------------------------------------------- launcher
extern "C" void kernel_launch(void* const* d_in, const int* in_sizes, int n_in,
                              void* d_out, int out_size, void* d_ws, size_t ws_size,
                              hipStream_t stream) {
    const float* x      = (const float*)d_in[0];
    const float* pos    = (const float*)d_in[1];
    const float* cond   = (const float*)d_in[2];
    const float* w_norm = (const float*)d_in[3];
    const float* w_qkv  = (const float*)d_in[4];
    const float* scale  = (const float*)d_in[5];
    const float* w_out  = (const float*)d_in[6];
    float* out = (float*)d_out;

    char* ws = (char*)d_ws;
    u16* xn     = (u16*)ws;                               // 8 MB (aliased by attn_o later)
    u16* wqkv_b = (u16*)(ws + (8u  << 20));               // 6 MB
    u16* wout_b = (u16*)(ws + (14u << 20));               // 2 MB
    float* cs   = (float*)(ws + (16u << 20));             // 8 KB
    u16* qb     = (u16*)(ws + (16u << 20) + (1u << 16));  // 8 MB
    const size_t HSZ = (size_t)BATCH * N_HEADS * SEQ * D_HEAD;
    u16* kb = qb + HSZ;                                   // 8 MB
    u16* vt = kb + HSZ;                                   // 8 MB (written permuted-transposed by gemm)
    u16* o_part   = (u16*)(ws + (41u << 20));             // Z x 8 MB bf16 partials
    float2* tab   = (float2*)(ws + (41u << 20));          // 2 MB rope table (dead before o_part written)
    u16* attn_o = xn;                                     // alias: xn dead after QKV GEMM

    const int Z = 2;   // split factor (R25: Z=2 halves partial traffic; 512 blocks still 2/CU)
    float* lsum_p = (float*)(ws + (41u << 20) + (size_t)Z * NTOK * D_MODEL * 2);

    prep_kernel<<<dim3(3584), dim3(256), 0, stream>>>(w_qkv, w_out, wqkv_b, wout_b,
                                                      cond, w_norm, cs, pos, (float2*)tab);
    rmsnorm_kernel<<<dim3(NTOK), dim3(256), 0, stream>>>(x, cs, xn);
    gemm_qkv<<<dim3(NTOK / 128, QKV_N / 128), dim3(512), 0, stream>>>(
        xn, wqkv_b, qb, kb, vt, scale, (const float2*)tab, NTOK, QKV_N, D_MODEL);
    attn_kernel<<<dim3(256 * Z), dim3(512), 0, stream>>>(
        qb, kb, vt, o_part, lsum_p);
    combine_kernel<<<dim3(NTOK * D_MODEL / 8 / 256), dim3(256), 0, stream>>>(o_part, lsum_p, attn_o, Z);
    gemm_out<<<dim3(NTOK / 128, D_MODEL / 64), dim3(256), 0, stream>>>(
        attn_o, wout_b, out, x, NTOK, D_MODEL, D_MODEL);
}